// Round 21
// baseline (109.000 us; speedup 1.0000x reference)
//
#include <hip/hip_runtime.h>

#define N_PTS  2048
#define BATCH  64
#define NSLICE 32
#define SLICE  (N_PTS / NSLICE)   // 64 search cols per block
#define P      8                  // rows per thread (8*256 = all 2048 rows)
#define BLK    256
#define BLK2   128                // K2 threads per block

static_assert(P * BLK == N_PTS, "block must cover all rows for col-final mins");
static_assert(SLICE <= BLK, "one staged point per thread");

// order-preserving float<->int key for signed-int atomicMin
__device__ __forceinline__ int fkey(float v) {
    int b = __float_as_int(v);
    return b >= 0 ? b : b ^ 0x7fffffff;
}
__device__ __forceinline__ float funkey(int b) {
    return __int_as_float(b >= 0 ? b : b ^ 0x7fffffff);
}

// ---------------------------------------------------------------------------
// K1: SYMMETRIC chamfer tile.  grid (NSLICE=32, BATCH) = 2048 blocks.
// BYTE-IDENTICAL to rounds 19/20 (measured 44.0-48.6us across runs, ±5%
// noise band; absmax=0): 8-col reduce period, 3-step half-exchange fold,
// all-lane LDS atomicMin commit.  Chain-restructure win (50.4->44) locked.
// ---------------------------------------------------------------------------
template <bool ATOMIC>
__global__ __launch_bounds__(BLK, 4) void chamfer_partial(
        const float4* __restrict__ p,
        const float4* __restrict__ q,
        float* __restrict__ wrow,   // plain: [BATCH][NSLICE][N_PTS] f32
                                    // atomic: [BATCH][N_PTS] int keys
        float* __restrict__ wcol,   // [BATCH][N_PTS] f32, block-exclusive
        float* __restrict__ out) {
    __shared__ float4 sQ[SLICE];        // 1 KB
    __shared__ float4 sQs4[SLICE / 4];  // 256 B
    __shared__ int    colk[SLICE];      // 256 B

    const int tid = threadIdx.x;
    const int s   = blockIdx.x;
    const int b   = blockIdx.y;
    const float4* __restrict__ Pb = p + (size_t)b * N_PTS;
    const float4* __restrict__ Qb = q + (size_t)b * N_PTS + s * SLICE;

    if (s == 0 && b == 0 && tid == 0) out[0] = 0.0f;

    if (tid < SLICE) {   // stage col slice + |q|^2 + init col keys
        const float4 v = Qb[tid];
        sQ[tid] = v;
        ((float*)sQs4)[tid] = v.x * v.x + v.y * v.y + v.z * v.z + v.w * v.w;
        colk[tid] = 0x7FFFFFFF;
    }
    __syncthreads();

    float4 pm[P];   // -2 * row point
    float  psq[P];  // |p|^2
    float  mn[P];   // row mins (carry psq folded in)
#pragma unroll
    for (int k = 0; k < P; ++k) {
        const float4 pv = Pb[tid + k * BLK];
        psq[k] = pv.x * pv.x + pv.y * pv.y + pv.z * pv.z + pv.w * pv.w;
        pm[k]  = make_float4(-2.0f * pv.x, -2.0f * pv.y, -2.0f * pv.z, -2.0f * pv.w);
        mn[k]  = 3.4e38f;
    }

    const int l = tid & 63;

#pragma unroll 1
    for (int jj = 0; jj < SLICE; jj += 8) {
        float c[8];
#pragma unroll
        for (int i = 0; i < 8; ++i) c[i] = 3.4e38f;

        // two 4-col compute sub-blocks (cols jj..jj+3, jj+4..jj+7)
#pragma unroll
        for (int h = 0; h < 2; ++h) {
            const int j = jj + 4 * h;
            const float4 qs = sQs4[j >> 2];
            const float4 q0 = sQ[j + 0];
            const float4 q1 = sQ[j + 1];
            const float4 q2 = sQ[j + 2];
            const float4 q3 = sQ[j + 3];
#pragma unroll
            for (int k = 0; k < P; k += 2) {
                const float4 a0 = pm[k], a1 = pm[k + 1];
                const float  e0 = psq[k], e1 = psq[k + 1];
                float u00 = fmaf(a0.x, q0.x, qs.x + e0);
                u00 = fmaf(a0.y, q0.y, u00); u00 = fmaf(a0.z, q0.z, u00); u00 = fmaf(a0.w, q0.w, u00);
                float u01 = fmaf(a0.x, q1.x, qs.y + e0);
                u01 = fmaf(a0.y, q1.y, u01); u01 = fmaf(a0.z, q1.z, u01); u01 = fmaf(a0.w, q1.w, u01);
                float u02 = fmaf(a0.x, q2.x, qs.z + e0);
                u02 = fmaf(a0.y, q2.y, u02); u02 = fmaf(a0.z, q2.z, u02); u02 = fmaf(a0.w, q2.w, u02);
                float u03 = fmaf(a0.x, q3.x, qs.w + e0);
                u03 = fmaf(a0.y, q3.y, u03); u03 = fmaf(a0.z, q3.z, u03); u03 = fmaf(a0.w, q3.w, u03);
                float u10 = fmaf(a1.x, q0.x, qs.x + e1);
                u10 = fmaf(a1.y, q0.y, u10); u10 = fmaf(a1.z, q0.z, u10); u10 = fmaf(a1.w, q0.w, u10);
                float u11 = fmaf(a1.x, q1.x, qs.y + e1);
                u11 = fmaf(a1.y, q1.y, u11); u11 = fmaf(a1.z, q1.z, u11); u11 = fmaf(a1.w, q1.w, u11);
                float u12 = fmaf(a1.x, q2.x, qs.z + e1);
                u12 = fmaf(a1.y, q2.y, u12); u12 = fmaf(a1.z, q2.z, u12); u12 = fmaf(a1.w, q2.w, u12);
                float u13 = fmaf(a1.x, q3.x, qs.w + e1);
                u13 = fmaf(a1.y, q3.y, u13); u13 = fmaf(a1.z, q3.z, u13); u13 = fmaf(a1.w, q3.w, u13);
                // row mins
                asm("v_min3_f32 %0, %0, %1, %2" : "+v"(mn[k])     : "v"(u00), "v"(u01));
                asm("v_min3_f32 %0, %0, %1, %2" : "+v"(mn[k])     : "v"(u02), "v"(u03));
                asm("v_min3_f32 %0, %0, %1, %2" : "+v"(mn[k + 1]) : "v"(u10), "v"(u11));
                asm("v_min3_f32 %0, %0, %1, %2" : "+v"(mn[k + 1]) : "v"(u12), "v"(u13));
                // col mins
                asm("v_min3_f32 %0, %0, %1, %2" : "+v"(c[4 * h + 0]) : "v"(u00), "v"(u10));
                asm("v_min3_f32 %0, %0, %1, %2" : "+v"(c[4 * h + 1]) : "v"(u01), "v"(u11));
                asm("v_min3_f32 %0, %0, %1, %2" : "+v"(c[4 * h + 2]) : "v"(u02), "v"(u12));
                asm("v_min3_f32 %0, %0, %1, %2" : "+v"(c[4 * h + 3]) : "v"(u03), "v"(u13));
            }
        }

        // 3-step half-exchange fold -> lane l holds col (l&7) min over its
        // 8-lane group; one all-lane atomicMin commit (no read-back chain).
        float r0, r1, r2, r3, t0, t1, m;
        {
            const bool b0 = (l & 1);
            const float s0 = b0 ? c[0] : c[1];
            const float s1 = b0 ? c[2] : c[3];
            const float s2 = b0 ? c[4] : c[5];
            const float s3 = b0 ? c[6] : c[7];
            const float k0 = b0 ? c[1] : c[0];
            const float k1 = b0 ? c[3] : c[2];
            const float k2 = b0 ? c[5] : c[4];
            const float k3 = b0 ? c[7] : c[6];
            r0 = fminf(k0, __shfl_xor(s0, 1, 64));
            r1 = fminf(k1, __shfl_xor(s1, 1, 64));
            r2 = fminf(k2, __shfl_xor(s2, 1, 64));
            r3 = fminf(k3, __shfl_xor(s3, 1, 64));
        }
        {
            const bool b1 = (l & 2);
            const float s0 = b1 ? r0 : r1;
            const float s1 = b1 ? r2 : r3;
            const float k0 = b1 ? r1 : r0;
            const float k1 = b1 ? r3 : r2;
            t0 = fminf(k0, __shfl_xor(s0, 2, 64));
            t1 = fminf(k1, __shfl_xor(s1, 2, 64));
        }
        {
            const bool b2 = (l & 4);
            const float s0 = b2 ? t0 : t1;
            const float k0 = b2 ? t1 : t0;
            m = fminf(k0, __shfl_xor(s0, 4, 64));
        }
        atomicMin(&colk[jj + (l & 7)], fkey(m));
    }

    // row epilogue (mn already includes psq via the u-chain)
    if (ATOMIC) {
        int* wi = (int*)wrow + (size_t)b * N_PTS;
#pragma unroll
        for (int k = 0; k < P; ++k)
            atomicMin(wi + tid + k * BLK, fkey(mn[k]));
    } else {
        float* wf = wrow + ((size_t)b * NSLICE + s) * N_PTS;
#pragma unroll
        for (int k = 0; k < P; ++k)
            wf[tid + k * BLK] = mn[k];
    }

    // col epilogue: block-final (all 2048 rows seen), block-exclusive range
    __syncthreads();
    if (tid < SLICE)
        wcol[(size_t)b * N_PTS + s * SLICE + tid] = funkey(colk[tid]);
}

// ---------------------------------------------------------------------------
// K2: merge + jet.  grid (4, BATCH) = 512 blocks x 128 thr (round-20's 128
// blocks = 0.5 blocks/CU left half the chip idle; round-19 showed the LDS-
// merge alternative loses, so keep thread-owns-float4 with 32 independent
// strided loads and just quadruple the block count).
// ---------------------------------------------------------------------------
template <bool ATOMIC>
__global__ __launch_bounds__(BLK2) void chamfer_finish(
        const float4* __restrict__ p,
        const float4* __restrict__ q,
        const float* __restrict__ wrow,
        const float* __restrict__ wcol,
        float* __restrict__ out) {
    __shared__ float wred[BLK2 / 64];
    __shared__ float4 wacc[BLK2 / 64];
    const int tid  = threadIdx.x;
    const int qi4  = blockIdx.x * BLK2 + tid;  // float4-granular index, 0..511
    const int b    = blockIdx.y;
    const int lane = tid & 63;
    const int wid  = tid >> 6;

    float acc;
    if (ATOMIC) {
        const int4 v = ((const int4*)wrow)[(size_t)b * (N_PTS / 4) + qi4];
        acc = funkey(v.x) + funkey(v.y) + funkey(v.z) + funkey(v.w);
    } else {
        const float4* wf = (const float4*)wrow + (size_t)b * NSLICE * (N_PTS / 4);
        float4 m = wf[qi4];
#pragma unroll
        for (int s2 = 1; s2 < NSLICE; ++s2) {
            const float4 v = wf[(size_t)s2 * (N_PTS / 4) + qi4];
            m.x = fminf(m.x, v.x); m.y = fminf(m.y, v.y);
            m.z = fminf(m.z, v.z); m.w = fminf(m.w, v.w);
        }
        acc = (m.x + m.y) + (m.z + m.w);
    }
    {   // column mins (already final)
        const float4 cv = ((const float4*)wcol)[(size_t)b * (N_PTS / 4) + qi4];
        acc += (cv.x + cv.y) + (cv.z + cv.w);
    }

#pragma unroll
    for (int off = 32; off > 0; off >>= 1) acc += __shfl_down(acc, off, 64);
    if (lane == 0) wred[wid] = acc;
    __syncthreads();
    if (tid == 0) {
        float sc = 0.f;
#pragma unroll
        for (int w = 0; w < BLK2 / 64; ++w) sc += wred[w];
        atomicAdd(out, sc);
    }

    // ---- jet term: x==0 block of each batch ----
    if (blockIdx.x == 0) {
        const float4* __restrict__ Pb = p + (size_t)b * N_PTS;
        const float4* __restrict__ Qb = q + (size_t)b * N_PTS;
        float ax = 0.f, ay = 0.f, az = 0.f, aw = 0.f;
        for (int j = tid; j < N_PTS; j += BLK2) {
            const float4 pv = Pb[j];
            const float4 qv = Qb[j];
            ax += pv.x - qv.x;
            ay += pv.y - qv.y;
            az += pv.z - qv.z;
            aw += pv.w - qv.w;
        }
#pragma unroll
        for (int off = 32; off > 0; off >>= 1) {
            ax += __shfl_down(ax, off, 64);
            ay += __shfl_down(ay, off, 64);
            az += __shfl_down(az, off, 64);
            aw += __shfl_down(aw, off, 64);
        }
        if (lane == 0) wacc[wid] = make_float4(ax, ay, az, aw);
        __syncthreads();   // block-uniform branch: safe
        if (tid == 0) {
            float dx = 0.f, dy = 0.f, dz = 0.f, dw = 0.f;
#pragma unroll
            for (int w = 0; w < BLK2 / 64; ++w) {
                dx += wacc[w].x; dy += wacc[w].y; dz += wacc[w].z; dw += wacc[w].w;
            }
            atomicAdd(out, dx * dx + dy * dy + dz * dz + dw * dw);
        }
    }
}

extern "C" void kernel_launch(void* const* d_in, const int* in_sizes, int n_in,
                              void* d_out, int out_size, void* d_ws, size_t ws_size,
                              hipStream_t stream) {
    const float4* p = (const float4*)d_in[0];
    const float4* q = (const float4*)d_in[1];
    float* out = (float*)d_out;
    float* ws  = (float*)d_ws;

    const size_t row_plain  = (size_t)BATCH * NSLICE * N_PTS;  // floats, 16 MB
    const size_t row_atomic = (size_t)BATCH * N_PTS;           // ints, 512 KB
    const size_t col_elems  = (size_t)BATCH * N_PTS;           // floats, 512 KB

    if (ws_size >= (row_plain + col_elems) * sizeof(float)) {
        // deterministic plain-store path: 2 dispatches, no memset
        float* wrow = ws;
        float* wcol = ws + row_plain;
        chamfer_partial<false><<<dim3(NSLICE, BATCH), BLK, 0, stream>>>(p, q, wrow, wcol, out);
        chamfer_finish<false><<<dim3(4, BATCH), BLK2, 0, stream>>>(p, q, wrow, wcol, out);
    } else {
        // compact 1 MB fallback: global atomicMin on int keys for rows
        float* wrow = ws;
        float* wcol = ws + row_atomic;
        hipMemsetAsync(wrow, 0x7F, row_atomic * sizeof(int), stream);
        chamfer_partial<true><<<dim3(NSLICE, BATCH), BLK, 0, stream>>>(p, q, wrow, wcol, out);
        chamfer_finish<true><<<dim3(4, BATCH), BLK2, 0, stream>>>(p, q, wrow, wcol, out);
    }
}

// Round 22
// 99.994 us; speedup vs baseline: 1.0901x; 1.0901x over previous
//
#include <hip/hip_runtime.h>

#define N_PTS  2048
#define BATCH  64
#define NSLICE 16
#define SLICE  (N_PTS / NSLICE)   // 128 search cols per block
#define P      8                  // rows per thread (8*256 = all 2048 rows)
#define BLK    256

static_assert(P * BLK == N_PTS, "block must cover all rows for col-final mins");
static_assert(SLICE <= BLK, "one staged point per thread");

// order-preserving float<->int key for signed-int atomicMin
__device__ __forceinline__ int fkey(float v) {
    int b = __float_as_int(v);
    return b >= 0 ? b : b ^ 0x7fffffff;
}
__device__ __forceinline__ float funkey(int b) {
    return __int_as_float(b >= 0 ? b : b ^ 0x7fffffff);
}

// ---------------------------------------------------------------------------
// K1: SYMMETRIC chamfer tile.  grid (NSLICE=16, BATCH) = 1024 blocks.
// Body identical to rounds 19-21 (8-col reduce period, 3-step half-exchange
// fold, all-lane LDS atomicMin commit; 44.0-48.6us at NSLICE=32, absmax=0).
// NSLICE 32->16 halves wrow (16->8MB) to cut K2's read; total fold work is
// slicing-invariant (16 periods x 1024 blocks = 8 x 2048).  Round-18 data
// puts the occupancy cost of 1024-vs-2048 blocks at ~+2us.
// Falsifier: K1 > 52us => revert to NSLICE=32.
// ---------------------------------------------------------------------------
template <bool ATOMIC>
__global__ __launch_bounds__(BLK, 4) void chamfer_partial(
        const float4* __restrict__ p,
        const float4* __restrict__ q,
        float* __restrict__ wrow,   // plain: [BATCH][NSLICE][N_PTS] f32
                                    // atomic: [BATCH][N_PTS] int keys
        float* __restrict__ wcol,   // [BATCH][N_PTS] f32, block-exclusive
        float* __restrict__ out) {
    __shared__ float4 sQ[SLICE];        // 2 KB
    __shared__ float4 sQs4[SLICE / 4];  // 512 B
    __shared__ int    colk[SLICE];      // 512 B

    const int tid = threadIdx.x;
    const int s   = blockIdx.x;
    const int b   = blockIdx.y;
    const float4* __restrict__ Pb = p + (size_t)b * N_PTS;
    const float4* __restrict__ Qb = q + (size_t)b * N_PTS + s * SLICE;

    if (s == 0 && b == 0 && tid == 0) out[0] = 0.0f;

    if (tid < SLICE) {   // stage col slice + |q|^2 + init col keys
        const float4 v = Qb[tid];
        sQ[tid] = v;
        ((float*)sQs4)[tid] = v.x * v.x + v.y * v.y + v.z * v.z + v.w * v.w;
        colk[tid] = 0x7FFFFFFF;
    }
    __syncthreads();

    float4 pm[P];   // -2 * row point
    float  psq[P];  // |p|^2
    float  mn[P];   // row mins (carry psq folded in)
#pragma unroll
    for (int k = 0; k < P; ++k) {
        const float4 pv = Pb[tid + k * BLK];
        psq[k] = pv.x * pv.x + pv.y * pv.y + pv.z * pv.z + pv.w * pv.w;
        pm[k]  = make_float4(-2.0f * pv.x, -2.0f * pv.y, -2.0f * pv.z, -2.0f * pv.w);
        mn[k]  = 3.4e38f;
    }

    const int l = tid & 63;

#pragma unroll 1
    for (int jj = 0; jj < SLICE; jj += 8) {
        float c[8];
#pragma unroll
        for (int i = 0; i < 8; ++i) c[i] = 3.4e38f;

        // two 4-col compute sub-blocks (cols jj..jj+3, jj+4..jj+7)
#pragma unroll
        for (int h = 0; h < 2; ++h) {
            const int j = jj + 4 * h;
            const float4 qs = sQs4[j >> 2];
            const float4 q0 = sQ[j + 0];
            const float4 q1 = sQ[j + 1];
            const float4 q2 = sQ[j + 2];
            const float4 q3 = sQ[j + 3];
#pragma unroll
            for (int k = 0; k < P; k += 2) {
                const float4 a0 = pm[k], a1 = pm[k + 1];
                const float  e0 = psq[k], e1 = psq[k + 1];
                float u00 = fmaf(a0.x, q0.x, qs.x + e0);
                u00 = fmaf(a0.y, q0.y, u00); u00 = fmaf(a0.z, q0.z, u00); u00 = fmaf(a0.w, q0.w, u00);
                float u01 = fmaf(a0.x, q1.x, qs.y + e0);
                u01 = fmaf(a0.y, q1.y, u01); u01 = fmaf(a0.z, q1.z, u01); u01 = fmaf(a0.w, q1.w, u01);
                float u02 = fmaf(a0.x, q2.x, qs.z + e0);
                u02 = fmaf(a0.y, q2.y, u02); u02 = fmaf(a0.z, q2.z, u02); u02 = fmaf(a0.w, q2.w, u02);
                float u03 = fmaf(a0.x, q3.x, qs.w + e0);
                u03 = fmaf(a0.y, q3.y, u03); u03 = fmaf(a0.z, q3.z, u03); u03 = fmaf(a0.w, q3.w, u03);
                float u10 = fmaf(a1.x, q0.x, qs.x + e1);
                u10 = fmaf(a1.y, q0.y, u10); u10 = fmaf(a1.z, q0.z, u10); u10 = fmaf(a1.w, q0.w, u10);
                float u11 = fmaf(a1.x, q1.x, qs.y + e1);
                u11 = fmaf(a1.y, q1.y, u11); u11 = fmaf(a1.z, q1.z, u11); u11 = fmaf(a1.w, q1.w, u11);
                float u12 = fmaf(a1.x, q2.x, qs.z + e1);
                u12 = fmaf(a1.y, q2.y, u12); u12 = fmaf(a1.z, q2.z, u12); u12 = fmaf(a1.w, q2.w, u12);
                float u13 = fmaf(a1.x, q3.x, qs.w + e1);
                u13 = fmaf(a1.y, q3.y, u13); u13 = fmaf(a1.z, q3.z, u13); u13 = fmaf(a1.w, q3.w, u13);
                // row mins
                asm("v_min3_f32 %0, %0, %1, %2" : "+v"(mn[k])     : "v"(u00), "v"(u01));
                asm("v_min3_f32 %0, %0, %1, %2" : "+v"(mn[k])     : "v"(u02), "v"(u03));
                asm("v_min3_f32 %0, %0, %1, %2" : "+v"(mn[k + 1]) : "v"(u10), "v"(u11));
                asm("v_min3_f32 %0, %0, %1, %2" : "+v"(mn[k + 1]) : "v"(u12), "v"(u13));
                // col mins
                asm("v_min3_f32 %0, %0, %1, %2" : "+v"(c[4 * h + 0]) : "v"(u00), "v"(u10));
                asm("v_min3_f32 %0, %0, %1, %2" : "+v"(c[4 * h + 1]) : "v"(u01), "v"(u11));
                asm("v_min3_f32 %0, %0, %1, %2" : "+v"(c[4 * h + 2]) : "v"(u02), "v"(u12));
                asm("v_min3_f32 %0, %0, %1, %2" : "+v"(c[4 * h + 3]) : "v"(u03), "v"(u13));
            }
        }

        // 3-step half-exchange fold -> lane l holds col (l&7) min over its
        // 8-lane group; one all-lane atomicMin commit (no read-back chain).
        float r0, r1, r2, r3, t0, t1, m;
        {
            const bool b0 = (l & 1);
            const float s0 = b0 ? c[0] : c[1];
            const float s1 = b0 ? c[2] : c[3];
            const float s2 = b0 ? c[4] : c[5];
            const float s3 = b0 ? c[6] : c[7];
            const float k0 = b0 ? c[1] : c[0];
            const float k1 = b0 ? c[3] : c[2];
            const float k2 = b0 ? c[5] : c[4];
            const float k3 = b0 ? c[7] : c[6];
            r0 = fminf(k0, __shfl_xor(s0, 1, 64));
            r1 = fminf(k1, __shfl_xor(s1, 1, 64));
            r2 = fminf(k2, __shfl_xor(s2, 1, 64));
            r3 = fminf(k3, __shfl_xor(s3, 1, 64));
        }
        {
            const bool b1 = (l & 2);
            const float s0 = b1 ? r0 : r1;
            const float s1 = b1 ? r2 : r3;
            const float k0 = b1 ? r1 : r0;
            const float k1 = b1 ? r3 : r2;
            t0 = fminf(k0, __shfl_xor(s0, 2, 64));
            t1 = fminf(k1, __shfl_xor(s1, 2, 64));
        }
        {
            const bool b2 = (l & 4);
            const float s0 = b2 ? t0 : t1;
            const float k0 = b2 ? t1 : t0;
            m = fminf(k0, __shfl_xor(s0, 4, 64));
        }
        atomicMin(&colk[jj + (l & 7)], fkey(m));
    }

    // row epilogue (mn already includes psq via the u-chain)
    if (ATOMIC) {
        int* wi = (int*)wrow + (size_t)b * N_PTS;
#pragma unroll
        for (int k = 0; k < P; ++k)
            atomicMin(wi + tid + k * BLK, fkey(mn[k]));
    } else {
        float* wf = wrow + ((size_t)b * NSLICE + s) * N_PTS;
#pragma unroll
        for (int k = 0; k < P; ++k)
            wf[tid + k * BLK] = mn[k];
    }

    // col epilogue: block-final (all 2048 rows seen), block-exclusive range
    __syncthreads();
    if (tid < SLICE)
        wcol[(size_t)b * N_PTS + s * SLICE + tid] = funkey(colk[tid]);
}

// ---------------------------------------------------------------------------
// K2: REVERTED to round-20's exact structure (proven 11us incl. overhead;
// round-21's (4,B)x128 variant cost 20us -- same 512 waves, just more
// per-block overhead).  grid (2, BATCH) x 256 thr, thread-owns-float4,
// NSLICE-deep independent strided merge (now 16-deep / 8MB).
// ---------------------------------------------------------------------------
template <bool ATOMIC>
__global__ __launch_bounds__(256) void chamfer_finish(
        const float4* __restrict__ p,
        const float4* __restrict__ q,
        const float* __restrict__ wrow,
        const float* __restrict__ wcol,
        float* __restrict__ out) {
    __shared__ float wred[4];
    __shared__ float4 wacc[4];
    const int tid  = threadIdx.x;
    const int qi4  = blockIdx.x * 256 + tid;   // float4-granular index, 0..511
    const int b    = blockIdx.y;
    const int lane = tid & 63;
    const int wid  = tid >> 6;

    float acc;
    if (ATOMIC) {
        const int4 v = ((const int4*)wrow)[(size_t)b * (N_PTS / 4) + qi4];
        acc = funkey(v.x) + funkey(v.y) + funkey(v.z) + funkey(v.w);
    } else {
        const float4* wf = (const float4*)wrow + (size_t)b * NSLICE * (N_PTS / 4);
        float4 m = wf[qi4];
#pragma unroll
        for (int s2 = 1; s2 < NSLICE; ++s2) {
            const float4 v = wf[(size_t)s2 * (N_PTS / 4) + qi4];
            m.x = fminf(m.x, v.x); m.y = fminf(m.y, v.y);
            m.z = fminf(m.z, v.z); m.w = fminf(m.w, v.w);
        }
        acc = (m.x + m.y) + (m.z + m.w);
    }
    {   // column mins (already final)
        const float4 cv = ((const float4*)wcol)[(size_t)b * (N_PTS / 4) + qi4];
        acc += (cv.x + cv.y) + (cv.z + cv.w);
    }

#pragma unroll
    for (int off = 32; off > 0; off >>= 1) acc += __shfl_down(acc, off, 64);
    if (lane == 0) wred[wid] = acc;
    __syncthreads();
    if (tid == 0) {
        atomicAdd(out, wred[0] + wred[1] + wred[2] + wred[3]);
    }

    // ---- jet term: x==0 block of each batch ----
    if (blockIdx.x == 0) {
        const float4* __restrict__ Pb = p + (size_t)b * N_PTS;
        const float4* __restrict__ Qb = q + (size_t)b * N_PTS;
        float ax = 0.f, ay = 0.f, az = 0.f, aw = 0.f;
        for (int j = tid; j < N_PTS; j += 256) {
            const float4 pv = Pb[j];
            const float4 qv = Qb[j];
            ax += pv.x - qv.x;
            ay += pv.y - qv.y;
            az += pv.z - qv.z;
            aw += pv.w - qv.w;
        }
#pragma unroll
        for (int off = 32; off > 0; off >>= 1) {
            ax += __shfl_down(ax, off, 64);
            ay += __shfl_down(ay, off, 64);
            az += __shfl_down(az, off, 64);
            aw += __shfl_down(aw, off, 64);
        }
        if (lane == 0) wacc[wid] = make_float4(ax, ay, az, aw);
        __syncthreads();   // block-uniform branch: safe
        if (tid == 0) {
            float dx = 0.f, dy = 0.f, dz = 0.f, dw = 0.f;
#pragma unroll
            for (int w = 0; w < 4; ++w) {
                dx += wacc[w].x; dy += wacc[w].y; dz += wacc[w].z; dw += wacc[w].w;
            }
            atomicAdd(out, dx * dx + dy * dy + dz * dz + dw * dw);
        }
    }
}

extern "C" void kernel_launch(void* const* d_in, const int* in_sizes, int n_in,
                              void* d_out, int out_size, void* d_ws, size_t ws_size,
                              hipStream_t stream) {
    const float4* p = (const float4*)d_in[0];
    const float4* q = (const float4*)d_in[1];
    float* out = (float*)d_out;
    float* ws  = (float*)d_ws;

    const size_t row_plain  = (size_t)BATCH * NSLICE * N_PTS;  // floats, 8 MB
    const size_t row_atomic = (size_t)BATCH * N_PTS;           // ints, 512 KB
    const size_t col_elems  = (size_t)BATCH * N_PTS;           // floats, 512 KB

    if (ws_size >= (row_plain + col_elems) * sizeof(float)) {
        // deterministic plain-store path: 2 dispatches, no memset
        float* wrow = ws;
        float* wcol = ws + row_plain;
        chamfer_partial<false><<<dim3(NSLICE, BATCH), BLK, 0, stream>>>(p, q, wrow, wcol, out);
        chamfer_finish<false><<<dim3(2, BATCH), 256, 0, stream>>>(p, q, wrow, wcol, out);
    } else {
        // compact 1 MB fallback: global atomicMin on int keys for rows
        float* wrow = ws;
        float* wcol = ws + row_atomic;
        hipMemsetAsync(wrow, 0x7F, row_atomic * sizeof(int), stream);
        chamfer_partial<true><<<dim3(NSLICE, BATCH), BLK, 0, stream>>>(p, q, wrow, wcol, out);
        chamfer_finish<true><<<dim3(2, BATCH), 256, 0, stream>>>(p, q, wrow, wcol, out);
    }
}